// Round 1
// baseline (744.296 us; speedup 1.0000x reference)
//
#include <hip/hip_runtime.h>
#include <stdint.h>

typedef __attribute__((ext_vector_type(8))) short short8;
typedef __attribute__((ext_vector_type(4))) float f32x4;

#define BH 96
#define T 1024
#define D 256

static __device__ __forceinline__ unsigned short f2bf(float x){
  uint32_t u = __float_as_uint(x);
  uint32_t r = (u + 0x7FFFu + ((u >> 16) & 1u)) >> 16;  // RNE
  return (unsigned short)r;
}

static __device__ __forceinline__ uint32_t cvtpk_bf16(float lo, float hi){
  uint32_t r;
  asm("v_cvt_pk_bf16_f32 %0, %1, %2" : "=v"(r) : "v"(lo), "v"(hi));
  return r;
}

// ---------------- Kernel 1: RoPE + 0.25 scale + bf16 cast -> QR[bh][t][n]
__global__ void k_rope(const float* __restrict__ Q, const float* __restrict__ freqs,
                       unsigned short* __restrict__ QR){
  long idx = (long)blockIdx.x * 256 + threadIdx.x;   // one float4 (2 rope pairs)
  long e = idx * 4;
  int n = (int)(e & (D - 1));
  int t = (int)((e >> 8) & (T - 1));
  float4 q = *(const float4*)(Q + e);
  float f0 = freqs[n];
  float f2 = freqs[n + 2];
  float ph0 = (float)t * f0; ph0 -= floorf(ph0);      // fractional turns
  float ph2 = (float)t * f2; ph2 -= floorf(ph2);
  float c0 = __builtin_amdgcn_cosf(ph0), s0 = __builtin_amdgcn_sinf(ph0); // sin/cos of 2*pi*x
  float c2 = __builtin_amdgcn_cosf(ph2), s2 = __builtin_amdgcn_sinf(ph2);
  float o0 = (q.x * c0 - q.y * s0) * 0.25f;
  float o1 = (q.y * c0 + q.x * s0) * 0.25f;
  float o2 = (q.z * c2 - q.w * s2) * 0.25f;
  float o3 = (q.w * c2 + q.z * s2) * 0.25f;
  ushort4 o;
  o.x = f2bf(o0); o.y = f2bf(o1); o.z = f2bf(o2); o.w = f2bf(o3);
  *(ushort4*)(QR + e) = o;
}

// ---------------- Kernel 2: V [bh][t][n] fp32 -> Vt [bh][n][t] bf16
__global__ void k_transpose(const float* __restrict__ V, unsigned short* __restrict__ Vt){
  __shared__ unsigned short L[64 * 66];   // [t_local][n_local], pitch 66 (bank skew)
  int bid = blockIdx.x;
  int head = bid >> 6;            // 64 tiles of 64x64 per head
  int rem = bid & 63;
  int t0 = (rem & 15) * 64;
  int n0 = (rem >> 4) * 64;
  int tid = threadIdx.x;
  const float* Vh = V + (long)head * T * D;
  unsigned short* Vth = Vt + (long)head * T * D;
  int lr = tid >> 4;              // 0..15
  int lc = (tid & 15) * 4;        // n offset
#pragma unroll
  for (int i = 0; i < 4; ++i){
    int tl = i * 16 + lr;
    float4 v = *(const float4*)(Vh + (long)(t0 + tl) * D + n0 + lc);
    uint32_t w0 = (uint32_t)f2bf(v.x) | ((uint32_t)f2bf(v.y) << 16);
    uint32_t w1 = (uint32_t)f2bf(v.z) | ((uint32_t)f2bf(v.w) << 16);
    *(uint32_t*)&L[tl * 66 + lc]     = w0;
    *(uint32_t*)&L[tl * 66 + lc + 2] = w1;
  }
  __syncthreads();
  int nr = tid >> 3;              // 0..31
  int t8 = (tid & 7) * 8;
#pragma unroll
  for (int i = 0; i < 2; ++i){
    int n_row = i * 32 + nr;
    unsigned short u[8];
#pragma unroll
    for (int j = 0; j < 8; ++j) u[j] = L[(t8 + j) * 66 + n_row];
    uint4 o;
    o.x = (uint32_t)u[0] | ((uint32_t)u[1] << 16);
    o.y = (uint32_t)u[2] | ((uint32_t)u[3] << 16);
    o.z = (uint32_t)u[4] | ((uint32_t)u[5] << 16);
    o.w = (uint32_t)u[6] | ((uint32_t)u[7] << 16);
    *(uint4*)(Vth + (long)(n0 + n_row) * T + t0 + t8) = o;
  }
}

// ---------------- Kernel 3: flash attention, K=Q=QR (pre-scaled), V from Vt
__global__ __launch_bounds__(256) void k_flash(const unsigned short* __restrict__ QR,
                                               const unsigned short* __restrict__ Vt,
                                               float* __restrict__ Out){
  int bid = blockIdx.x;
  int logical = (bid & 7) * 192 + (bid >> 3);  // bijective XCD swizzle (1536 % 8 == 0)
  int head  = logical >> 4;
  int qtile = logical & 15;
  int wid  = threadIdx.x >> 6;
  int lane = threadIdx.x & 63;
  int q15 = lane & 15;
  int g   = lane >> 4;
  const unsigned short* qr = QR + (long)head * T * D;
  const unsigned short* vt = Vt + (long)head * T * D;
  int qb = qtile * 64 + wid * 16;

  // Q fragments: B-operand of swapped QK^T; lane holds Q[qb+q15][c*32 + g*8 + j]
  short8 qf[8];
#pragma unroll
  for (int c = 0; c < 8; ++c)
    qf[c] = *(const short8*)(qr + (long)(qb + q15) * D + c * 32 + g * 8);

  f32x4 acc[16];
#pragma unroll
  for (int i = 0; i < 16; ++i) acc[i] = f32x4{0.f, 0.f, 0.f, 0.f};
  float m = -3e38f, lsum = 0.f;

  for (int kb = 0; kb < T; kb += 32){
    f32x4 st0 = f32x4{0.f, 0.f, 0.f, 0.f};
    f32x4 st1 = f32x4{0.f, 0.f, 0.f, 0.f};
    const unsigned short* k0p = qr + (long)(kb + q15) * D + g * 8;
    const unsigned short* k1p = k0p + 16 * D;
#pragma unroll
    for (int c = 0; c < 8; ++c){
      short8 kf0 = *(const short8*)(k0p + c * 32);
      short8 kf1 = *(const short8*)(k1p + c * 32);
      st0 = __builtin_amdgcn_mfma_f32_16x16x32_bf16(kf0, qf[c], st0, 0, 0, 0);
      st1 = __builtin_amdgcn_mfma_f32_16x16x32_bf16(kf1, qf[c], st1, 0, 0, 0);
    }
    // lane owns query q15; scores for keys kb+g*4+r (st0) and kb+16+g*4+r (st1)
    float tm = fmaxf(fmaxf(fmaxf(st0.x, st0.y), fmaxf(st0.z, st0.w)),
                     fmaxf(fmaxf(st1.x, st1.y), fmaxf(st1.z, st1.w)));
    tm = fmaxf(tm, __shfl_xor(tm, 16));
    tm = fmaxf(tm, __shfl_xor(tm, 32));
    float mnew = fmaxf(m, tm);
    float alpha = __expf(m - mnew);
    float p00 = __expf(st0.x - mnew), p01 = __expf(st0.y - mnew);
    float p02 = __expf(st0.z - mnew), p03 = __expf(st0.w - mnew);
    float p10 = __expf(st1.x - mnew), p11 = __expf(st1.y - mnew);
    float p12 = __expf(st1.z - mnew), p13 = __expf(st1.w - mnew);
    float ts = ((p00 + p01) + (p02 + p03)) + ((p10 + p11) + (p12 + p13));
    ts += __shfl_xor(ts, 16);
    ts += __shfl_xor(ts, 32);
    lsum = lsum * alpha + ts;
    if (__any(tm > m)){   // rescale O only when the running max grew (wave-uniform)
      float a0 = __shfl(alpha, g * 4 + 0);
      float a1 = __shfl(alpha, g * 4 + 1);
      float a2 = __shfl(alpha, g * 4 + 2);
      float a3 = __shfl(alpha, g * 4 + 3);
#pragma unroll
      for (int nc = 0; nc < 16; ++nc){
        acc[nc].x *= a0; acc[nc].y *= a1; acc[nc].z *= a2; acc[nc].w *= a3;
      }
    }
    m = mnew;
    // pack P to bf16 pairs: t0w0 = keys g*4+{0,1}, t0w1 = g*4+{2,3}; t1* = +16
    uint32_t t0w0 = cvtpk_bf16(p00, p01), t0w1 = cvtpk_bf16(p02, p03);
    uint32_t t1w0 = cvtpk_bf16(p10, p11), t1w1 = cvtpk_bf16(p12, p13);
    // redistribute into A-fragment layout: dest lane (g,q) needs keys g*8..g*8+7
    int s0l = ((g & 1) << 5) | q15;       // src group (g&1)*2
    int s1l = s0l + 16;                    // src group (g&1)*2 + 1
    uint32_t x0 = __shfl(t0w0, s0l), x1 = __shfl(t0w1, s0l);
    uint32_t X0 = __shfl(t1w0, s0l), X1 = __shfl(t1w1, s0l);
    uint32_t y0 = __shfl(t0w0, s1l), y1 = __shfl(t0w1, s1l);
    uint32_t Y0 = __shfl(t1w0, s1l), Y1 = __shfl(t1w1, s1l);
    bool lo = (g < 2);
    uint4 aws;
    aws.x = lo ? x0 : X0;   // keys g*8+{0,1}
    aws.y = lo ? x1 : X1;   // keys g*8+{2,3}
    aws.z = lo ? y0 : Y0;   // keys g*8+{4,5}
    aws.w = lo ? y1 : Y1;   // keys g*8+{6,7}
    short8 pa = __builtin_bit_cast(short8, aws);
    // PV: O[q][n] += P * V ; B-frag from Vt is contiguous 16B
    const unsigned short* vp = vt + (long)q15 * T + kb + g * 8;
#pragma unroll
    for (int nc = 0; nc < 16; ++nc){
      short8 vf = *(const short8*)(vp + (long)nc * 16 * T);
      acc[nc] = __builtin_amdgcn_mfma_f32_16x16x32_bf16(pa, vf, acc[nc], 0, 0, 0);
    }
  }
  float rl = 1.0f / lsum;
  float d0 = __shfl(rl, g * 4 + 0);
  float d1 = __shfl(rl, g * 4 + 1);
  float d2 = __shfl(rl, g * 4 + 2);
  float d3 = __shfl(rl, g * 4 + 3);
  float* op = Out + (long)head * T * D + (long)qb * D;
#pragma unroll
  for (int nc = 0; nc < 16; ++nc){
    float* o = op + nc * 16 + q15;
    o[(g * 4 + 0) * D] = acc[nc].x * d0;
    o[(g * 4 + 1) * D] = acc[nc].y * d1;
    o[(g * 4 + 2) * D] = acc[nc].z * d2;
    o[(g * 4 + 3) * D] = acc[nc].w * d3;
  }
}

extern "C" void kernel_launch(void* const* d_in, const int* in_sizes, int n_in,
                              void* d_out, int out_size, void* d_ws, size_t ws_size,
                              hipStream_t stream){
  (void)in_sizes; (void)n_in; (void)out_size; (void)ws_size;
  const float* Q     = (const float*)d_in[0];
  const float* V     = (const float*)d_in[1];
  const float* freqs = (const float*)d_in[2];
  float* Out = (float*)d_out;
  unsigned short* QR = (unsigned short*)d_ws;                  // [96][1024][256] bf16
  unsigned short* Vt = QR + (size_t)BH * T * D;                // [96][256][1024] bf16
  k_rope<<<dim3((BH * T * D) / 4 / 256), dim3(256), 0, stream>>>(Q, freqs, QR);
  k_transpose<<<dim3(BH * 64), dim3(256), 0, stream>>>(V, Vt);
  k_flash<<<dim3(BH * 16), dim3(256), 0, stream>>>(QR, Vt, Out);
}

// Round 2
// 331.057 us; speedup vs baseline: 2.2482x; 2.2482x over previous
//
#include <hip/hip_runtime.h>
#include <stdint.h>

typedef __attribute__((ext_vector_type(8))) short short8;
typedef __attribute__((ext_vector_type(4))) float f32x4;

#define BH 96
#define T 1024
#define D 256

static __device__ __forceinline__ unsigned short f2bf(float x){
  uint32_t u = __float_as_uint(x);
  uint32_t r = (u + 0x7FFFu + ((u >> 16) & 1u)) >> 16;  // RNE
  return (unsigned short)r;
}

static __device__ __forceinline__ uint32_t cvtpk_bf16(float lo, float hi){
  uint32_t r;
  asm("v_cvt_pk_bf16_f32 %0, %1, %2" : "=v"(r) : "v"(lo), "v"(hi));
  return r;
}

static __device__ __forceinline__ void gload_lds16(const void* g, void* l){
  __builtin_amdgcn_global_load_lds((const __attribute__((address_space(1))) void*)g,
                                   (__attribute__((address_space(3))) void*)l, 16, 0, 0);
}

// ---------------- Kernel 1: RoPE + 0.25 scale + bf16 cast -> QR[bh][t][n]
__global__ void k_rope(const float* __restrict__ Q, const float* __restrict__ freqs,
                       unsigned short* __restrict__ QR){
  long idx = (long)blockIdx.x * 256 + threadIdx.x;   // one float4 (2 rope pairs)
  long e = idx * 4;
  int n = (int)(e & (D - 1));
  int t = (int)((e >> 8) & (T - 1));
  float4 q = *(const float4*)(Q + e);
  float f0 = freqs[n];
  float f2 = freqs[n + 2];
  float ph0 = (float)t * f0; ph0 -= floorf(ph0);      // fractional turns
  float ph2 = (float)t * f2; ph2 -= floorf(ph2);
  float c0 = __builtin_amdgcn_cosf(ph0), s0 = __builtin_amdgcn_sinf(ph0);
  float c2 = __builtin_amdgcn_cosf(ph2), s2 = __builtin_amdgcn_sinf(ph2);
  float o0 = (q.x * c0 - q.y * s0) * 0.25f;
  float o1 = (q.y * c0 + q.x * s0) * 0.25f;
  float o2 = (q.z * c2 - q.w * s2) * 0.25f;
  float o3 = (q.w * c2 + q.z * s2) * 0.25f;
  ushort4 o;
  o.x = f2bf(o0); o.y = f2bf(o1); o.z = f2bf(o2); o.w = f2bf(o3);
  *(ushort4*)(QR + e) = o;
}

// ---------------- Kernel 2: V [bh][t][n] fp32 -> Vt [bh][n][t] bf16
__global__ void k_transpose(const float* __restrict__ V, unsigned short* __restrict__ Vt){
  __shared__ unsigned short L[64 * 66];
  int bid = blockIdx.x;
  int head = bid >> 6;
  int rem = bid & 63;
  int t0 = (rem & 15) * 64;
  int n0 = (rem >> 4) * 64;
  int tid = threadIdx.x;
  const float* Vh = V + (long)head * T * D;
  unsigned short* Vth = Vt + (long)head * T * D;
  int lr = tid >> 4;
  int lc = (tid & 15) * 4;
#pragma unroll
  for (int i = 0; i < 4; ++i){
    int tl = i * 16 + lr;
    float4 v = *(const float4*)(Vh + (long)(t0 + tl) * D + n0 + lc);
    uint32_t w0 = (uint32_t)f2bf(v.x) | ((uint32_t)f2bf(v.y) << 16);
    uint32_t w1 = (uint32_t)f2bf(v.z) | ((uint32_t)f2bf(v.w) << 16);
    *(uint32_t*)&L[tl * 66 + lc]     = w0;
    *(uint32_t*)&L[tl * 66 + lc + 2] = w1;
  }
  __syncthreads();
  int nr = tid >> 3;
  int t8 = (tid & 7) * 8;
#pragma unroll
  for (int i = 0; i < 2; ++i){
    int n_row = i * 32 + nr;
    unsigned short u[8];
#pragma unroll
    for (int j = 0; j < 8; ++j) u[j] = L[(t8 + j) * 66 + n_row];
    uint4 o;
    o.x = (uint32_t)u[0] | ((uint32_t)u[1] << 16);
    o.y = (uint32_t)u[2] | ((uint32_t)u[3] << 16);
    o.z = (uint32_t)u[4] | ((uint32_t)u[5] << 16);
    o.w = (uint32_t)u[6] | ((uint32_t)u[7] << 16);
    *(uint4*)(Vth + (long)(n0 + n_row) * T + t0 + t8) = o;
  }
}

// ---------------- Kernel 3: flash attention with LDS-staged K/V tiles
// Block: 512 thr (8 waves), q-tile 128 (16 rows/wave). KTILE=32 keys/step.
// LDS per buffer: K 16KB as [half2][c8][g4][row16][16B], V 16KB as [nc16][g4][q16][16B]
//  -> every ds_read_b128 is lane-linear contiguous (conflict-free); content
//     permutation done via per-lane pre-swizzled global source addresses.
__global__ __launch_bounds__(512, 4) void k_flash(const unsigned short* __restrict__ QR,
                                                  const unsigned short* __restrict__ Vt,
                                                  float* __restrict__ Out){
  __shared__ short lds[2][16384];   // [buf][ K:0..8191 | V:8192..16383 ] shorts (64KB)
  int tid = threadIdx.x;
  int wid = tid >> 6, lane = tid & 63;
  int q15 = lane & 15, g = lane >> 4;

  // XCD-bijective swizzle: 8 q-blocks of a head land on one XCD; 4 heads/XCD L2-warm
  int b = blockIdx.x;
  int x = b & 7, s = b >> 3;
  int qt = s & 7, hg = s >> 3;
  int head = hg * 8 + x;

  const unsigned short* qr = QR + (long)head * T * D;
  const unsigned short* vt = Vt + (long)head * T * D;
  int qb = qt * 128 + wid * 16;

  // staging source offsets (in shorts) for this thread's two 16B chunks of K and V
  int i0 = tid, i1 = tid + 512;
  int bK0 = (((i0 >> 9) * 16 + (i0 & 15)) * 256) + ((i0 >> 6) & 7) * 32 + ((i0 >> 4) & 3) * 8;
  int bK1 = (((i1 >> 9) * 16 + (i1 & 15)) * 256) + ((i1 >> 6) & 7) * 32 + ((i1 >> 4) & 3) * 8;
  int bV0 = ((i0 >> 6) * 16 + (i0 & 15)) * 1024 + ((i0 >> 4) & 3) * 8;
  int bV1 = ((i1 >> 6) * 16 + (i1 & 15)) * 1024 + ((i1 >> 4) & 3) * 8;

  // Q fragments: lane holds Q[qb+q15][c*32 + g*8 + j]
  short8 qf[8];
#pragma unroll
  for (int c = 0; c < 8; ++c)
    qf[c] = *(const short8*)(qr + (long)(qb + q15) * D + c * 32 + g * 8);

  f32x4 acc[16];
#pragma unroll
  for (int i = 0; i < 16; ++i) acc[i] = f32x4{0.f, 0.f, 0.f, 0.f};
  float m = -3e38f, lsum = 0.f;

  // prologue: stage tile 0 into buf 0
  {
    const unsigned short* sk = qr;          // kb = 0
    const unsigned short* sv = vt;
    gload_lds16(sk + bK0, &lds[0][i0 * 8]);
    gload_lds16(sk + bK1, &lds[0][i1 * 8]);
    gload_lds16(sv + bV0, &lds[0][8192 + i0 * 8]);
    gload_lds16(sv + bV1, &lds[0][8192 + i1 * 8]);
  }
  asm volatile("s_waitcnt vmcnt(0)" ::: "memory");
  __syncthreads();

  int buf = 0;
  for (int kb = 0; kb < T; kb += 32){
    // prefetch next tile into buf^1 (overlaps with compute below)
    if (kb + 32 < T){
      const unsigned short* sk = qr + (long)(kb + 32) * 256;
      const unsigned short* sv = vt + (kb + 32);
      gload_lds16(sk + bK0, &lds[buf ^ 1][i0 * 8]);
      gload_lds16(sk + bK1, &lds[buf ^ 1][i1 * 8]);
      gload_lds16(sv + bV0, &lds[buf ^ 1][8192 + i0 * 8]);
      gload_lds16(sv + bV1, &lds[buf ^ 1][8192 + i1 * 8]);
    }
    const short* ldsK = &lds[buf][0];
    const short* ldsV = &lds[buf][8192];

    f32x4 st0 = f32x4{0.f, 0.f, 0.f, 0.f};
    f32x4 st1 = f32x4{0.f, 0.f, 0.f, 0.f};
#pragma unroll
    for (int c = 0; c < 8; ++c){
      short8 kf0 = *(const short8*)&ldsK[c * 512 + lane * 8];
      short8 kf1 = *(const short8*)&ldsK[4096 + c * 512 + lane * 8];
      st0 = __builtin_amdgcn_mfma_f32_16x16x32_bf16(kf0, qf[c], st0, 0, 0, 0);
      st1 = __builtin_amdgcn_mfma_f32_16x16x32_bf16(kf1, qf[c], st1, 0, 0, 0);
    }
    // lane owns query q15; scores for keys kb+g*4+r (st0) and kb+16+g*4+r (st1)
    float tm = fmaxf(fmaxf(fmaxf(st0.x, st0.y), fmaxf(st0.z, st0.w)),
                     fmaxf(fmaxf(st1.x, st1.y), fmaxf(st1.z, st1.w)));
    tm = fmaxf(tm, __shfl_xor(tm, 16));
    tm = fmaxf(tm, __shfl_xor(tm, 32));
    float mnew = fmaxf(m, tm);
    float alpha = __expf(m - mnew);
    float p00 = __expf(st0.x - mnew), p01 = __expf(st0.y - mnew);
    float p02 = __expf(st0.z - mnew), p03 = __expf(st0.w - mnew);
    float p10 = __expf(st1.x - mnew), p11 = __expf(st1.y - mnew);
    float p12 = __expf(st1.z - mnew), p13 = __expf(st1.w - mnew);
    float ts = ((p00 + p01) + (p02 + p03)) + ((p10 + p11) + (p12 + p13));
    ts += __shfl_xor(ts, 16);
    ts += __shfl_xor(ts, 32);
    lsum = lsum * alpha + ts;
    if (__any(tm > m)){
      float a0 = __shfl(alpha, g * 4 + 0);
      float a1 = __shfl(alpha, g * 4 + 1);
      float a2 = __shfl(alpha, g * 4 + 2);
      float a3 = __shfl(alpha, g * 4 + 3);
#pragma unroll
      for (int nc = 0; nc < 16; ++nc){
        acc[nc].x *= a0; acc[nc].y *= a1; acc[nc].z *= a2; acc[nc].w *= a3;
      }
    }
    m = mnew;
    uint32_t t0w0 = cvtpk_bf16(p00, p01), t0w1 = cvtpk_bf16(p02, p03);
    uint32_t t1w0 = cvtpk_bf16(p10, p11), t1w1 = cvtpk_bf16(p12, p13);
    int s0l = ((g & 1) << 5) | q15;
    int s1l = s0l + 16;
    uint32_t x0 = __shfl(t0w0, s0l), x1 = __shfl(t0w1, s0l);
    uint32_t X0 = __shfl(t1w0, s0l), X1 = __shfl(t1w1, s0l);
    uint32_t y0 = __shfl(t0w0, s1l), y1 = __shfl(t0w1, s1l);
    uint32_t Y0 = __shfl(t1w0, s1l), Y1 = __shfl(t1w1, s1l);
    bool lo = (g < 2);
    uint4 aws;
    aws.x = lo ? x0 : X0;
    aws.y = lo ? x1 : X1;
    aws.z = lo ? y0 : Y0;
    aws.w = lo ? y1 : Y1;
    short8 pa = __builtin_bit_cast(short8, aws);
#pragma unroll
    for (int nc = 0; nc < 16; ++nc){
      short8 vf = *(const short8*)&ldsV[nc * 512 + lane * 8];
      acc[nc] = __builtin_amdgcn_mfma_f32_16x16x32_bf16(pa, vf, acc[nc], 0, 0, 0);
    }
    // next tile's loads must be complete before all waves flip buffers
    asm volatile("s_waitcnt vmcnt(0)" ::: "memory");
    __syncthreads();
    buf ^= 1;
  }

  float rl = 1.0f / lsum;
  float d0 = __shfl(rl, g * 4 + 0);
  float d1 = __shfl(rl, g * 4 + 1);
  float d2 = __shfl(rl, g * 4 + 2);
  float d3 = __shfl(rl, g * 4 + 3);
  float* op = Out + (long)head * T * D + (long)qb * D;
#pragma unroll
  for (int nc = 0; nc < 16; ++nc){
    float* o = op + nc * 16 + q15;
    o[(g * 4 + 0) * D] = acc[nc].x * d0;
    o[(g * 4 + 1) * D] = acc[nc].y * d1;
    o[(g * 4 + 2) * D] = acc[nc].z * d2;
    o[(g * 4 + 3) * D] = acc[nc].w * d3;
  }
}

extern "C" void kernel_launch(void* const* d_in, const int* in_sizes, int n_in,
                              void* d_out, int out_size, void* d_ws, size_t ws_size,
                              hipStream_t stream){
  (void)in_sizes; (void)n_in; (void)out_size; (void)ws_size;
  const float* Q     = (const float*)d_in[0];
  const float* V     = (const float*)d_in[1];
  const float* freqs = (const float*)d_in[2];
  float* Out = (float*)d_out;
  unsigned short* QR = (unsigned short*)d_ws;                  // [96][1024][256] bf16
  unsigned short* Vt = QR + (size_t)BH * T * D;                // [96][256][1024] bf16
  k_rope<<<dim3((BH * T * D) / 4 / 256), dim3(256), 0, stream>>>(Q, freqs, QR);
  k_transpose<<<dim3(BH * 64), dim3(256), 0, stream>>>(V, Vt);
  k_flash<<<dim3(BH * 8), dim3(512), 0, stream>>>(QR, Vt, Out);
}

// Round 3
// 189.836 us; speedup vs baseline: 3.9207x; 1.7439x over previous
//
#include <hip/hip_runtime.h>
#include <stdint.h>

typedef __attribute__((ext_vector_type(8))) short short8;
typedef __attribute__((ext_vector_type(4))) float f32x4;

#define BH 96
#define T 1024
#define D 256

static __device__ __forceinline__ unsigned short f2bf(float x){
  uint32_t u = __float_as_uint(x);
  uint32_t r = (u + 0x7FFFu + ((u >> 16) & 1u)) >> 16;  // RNE
  return (unsigned short)r;
}

static __device__ __forceinline__ uint32_t cvtpk_bf16(float lo, float hi){
  uint32_t r;
  asm("v_cvt_pk_bf16_f32 %0, %1, %2" : "=v"(r) : "v"(lo), "v"(hi));
  return r;
}

static __device__ __forceinline__ float exp2_fast(float x){
  float r;
  asm("v_exp_f32 %0, %1" : "=v"(r) : "v"(x));
  return r;
}

static __device__ __forceinline__ void gload_lds16(const void* g, void* l){
  __builtin_amdgcn_global_load_lds((const __attribute__((address_space(1))) void*)g,
                                   (__attribute__((address_space(3))) void*)l, 16, 0, 0);
}

// ---------------- Kernel 1: RoPE + (0.25*sqrt(log2e)) scale + bf16 cast
// Scores then come out in log2-domain: softmax via raw v_exp_f32 (=exp2), exact.
__global__ void k_rope(const float* __restrict__ Q, const float* __restrict__ freqs,
                       unsigned short* __restrict__ QR){
  const float SC = 0.25f * 1.20112241f;   // 0.25 * sqrt(log2(e))
  long idx = (long)blockIdx.x * 256 + threadIdx.x;
  long e = idx * 4;
  int n = (int)(e & (D - 1));
  int t = (int)((e >> 8) & (T - 1));
  float4 q = *(const float4*)(Q + e);
  float f0 = freqs[n];
  float f2 = freqs[n + 2];
  float ph0 = (float)t * f0; ph0 -= floorf(ph0);
  float ph2 = (float)t * f2; ph2 -= floorf(ph2);
  float c0 = __builtin_amdgcn_cosf(ph0), s0 = __builtin_amdgcn_sinf(ph0);
  float c2 = __builtin_amdgcn_cosf(ph2), s2 = __builtin_amdgcn_sinf(ph2);
  float o0 = (q.x * c0 - q.y * s0) * SC;
  float o1 = (q.y * c0 + q.x * s0) * SC;
  float o2 = (q.z * c2 - q.w * s2) * SC;
  float o3 = (q.w * c2 + q.z * s2) * SC;
  ushort4 o;
  o.x = f2bf(o0); o.y = f2bf(o1); o.z = f2bf(o2); o.w = f2bf(o3);
  *(ushort4*)(QR + e) = o;
}

// ---------------- Kernel 2: V [bh][t][n] fp32 -> Vt [bh][n][t] bf16
__global__ void k_transpose(const float* __restrict__ V, unsigned short* __restrict__ Vt){
  __shared__ unsigned short L[64 * 66];
  int bid = blockIdx.x;
  int head = bid >> 6;
  int rem = bid & 63;
  int t0 = (rem & 15) * 64;
  int n0 = (rem >> 4) * 64;
  int tid = threadIdx.x;
  const float* Vh = V + (long)head * T * D;
  unsigned short* Vth = Vt + (long)head * T * D;
  int lr = tid >> 4;
  int lc = (tid & 15) * 4;
#pragma unroll
  for (int i = 0; i < 4; ++i){
    int tl = i * 16 + lr;
    float4 v = *(const float4*)(Vh + (long)(t0 + tl) * D + n0 + lc);
    uint32_t w0 = (uint32_t)f2bf(v.x) | ((uint32_t)f2bf(v.y) << 16);
    uint32_t w1 = (uint32_t)f2bf(v.z) | ((uint32_t)f2bf(v.w) << 16);
    *(uint32_t*)&L[tl * 66 + lc]     = w0;
    *(uint32_t*)&L[tl * 66 + lc + 2] = w1;
  }
  __syncthreads();
  int nr = tid >> 3;
  int t8 = (tid & 7) * 8;
#pragma unroll
  for (int i = 0; i < 2; ++i){
    int n_row = i * 32 + nr;
    unsigned short u[8];
#pragma unroll
    for (int j = 0; j < 8; ++j) u[j] = L[(t8 + j) * 66 + n_row];
    uint4 o;
    o.x = (uint32_t)u[0] | ((uint32_t)u[1] << 16);
    o.y = (uint32_t)u[2] | ((uint32_t)u[3] << 16);
    o.z = (uint32_t)u[4] | ((uint32_t)u[5] << 16);
    o.w = (uint32_t)u[6] | ((uint32_t)u[7] << 16);
    *(uint4*)(Vth + (long)(n0 + n_row) * T + t0 + t8) = o;
  }
}

// Per-subtile softmax step (log2-domain scores). Defer-max: only reduce/rescale
// when the vote says some row's max grew past m+11 (~8 nats of headroom).
static __device__ __forceinline__ short8 softmax_step(
    f32x4 st0, f32x4 st1, float& m, float& lsum, f32x4* acc, int q15, int g)
{
  float lm = fmaxf(fmaxf(fmaxf(st0.x, st0.y), fmaxf(st0.z, st0.w)),
                   fmaxf(fmaxf(st1.x, st1.y), fmaxf(st1.z, st1.w)));
  if (__any(lm > m + 11.0f)){
    float tm = fmaxf(lm, __shfl_xor(lm, 16));
    tm = fmaxf(tm, __shfl_xor(tm, 32));
    float mnew = fmaxf(m, tm);
    float alpha = exp2_fast(m - mnew);     // m=-3e38 on first tile -> alpha=0
    float a0 = __shfl(alpha, g * 4 + 0);
    float a1 = __shfl(alpha, g * 4 + 1);
    float a2 = __shfl(alpha, g * 4 + 2);
    float a3 = __shfl(alpha, g * 4 + 3);
#pragma unroll
    for (int nc = 0; nc < 16; ++nc){
      acc[nc].x *= a0; acc[nc].y *= a1; acc[nc].z *= a2; acc[nc].w *= a3;
    }
    lsum *= alpha;
    m = mnew;
  }
  float p00 = exp2_fast(st0.x - m), p01 = exp2_fast(st0.y - m);
  float p02 = exp2_fast(st0.z - m), p03 = exp2_fast(st0.w - m);
  float p10 = exp2_fast(st1.x - m), p11 = exp2_fast(st1.y - m);
  float p12 = exp2_fast(st1.z - m), p13 = exp2_fast(st1.w - m);
  float ts = ((p00 + p01) + (p02 + p03)) + ((p10 + p11) + (p12 + p13));
  ts += __shfl_xor(ts, 16);
  ts += __shfl_xor(ts, 32);
  lsum += ts;
  uint32_t t0w0 = cvtpk_bf16(p00, p01), t0w1 = cvtpk_bf16(p02, p03);
  uint32_t t1w0 = cvtpk_bf16(p10, p11), t1w1 = cvtpk_bf16(p12, p13);
  int s0l = ((g & 1) << 5) | q15;
  int s1l = s0l + 16;
  uint32_t x0 = __shfl(t0w0, s0l), x1 = __shfl(t0w1, s0l);
  uint32_t X0 = __shfl(t1w0, s0l), X1 = __shfl(t1w1, s0l);
  uint32_t y0 = __shfl(t0w0, s1l), y1 = __shfl(t0w1, s1l);
  uint32_t Y0 = __shfl(t1w0, s1l), Y1 = __shfl(t1w1, s1l);
  bool lo = (g < 2);
  uint4 aws;
  aws.x = lo ? x0 : X0;
  aws.y = lo ? x1 : X1;
  aws.z = lo ? y0 : Y0;
  aws.w = lo ? y1 : Y1;
  return __builtin_bit_cast(short8, aws);
}

// ---------------- Kernel 3: flash attention, 4 waves x 32 q-rows (q-tile 128)
// KTILE=32 keys/step, double-buffered LDS (64KB). Each LDS K/V fragment read
// feeds TWO MFMAs (q-subtiles A and B) -> LDS bytes per FLOP halved vs 8x16.
__global__ __launch_bounds__(256, 2) void k_flash(const unsigned short* __restrict__ QR,
                                                  const unsigned short* __restrict__ Vt,
                                                  float* __restrict__ Out){
  __shared__ short lds[2][16384];   // [buf][ K:0..8191 | V:8192..16383 ]
  int tid = threadIdx.x;
  int wid = tid >> 6, lane = tid & 63;
  int q15 = lane & 15, g = lane >> 4;

  int b = blockIdx.x;
  int x = b & 7, s = b >> 3;
  int qt = s & 7, hg = s >> 3;
  int head = hg * 8 + x;            // XCD-bijective: one head's 8 q-blocks per XCD

  const unsigned short* qr = QR + (long)head * T * D;
  const unsigned short* vt = Vt + (long)head * T * D;
  int qb = qt * 128 + wid * 32;

  // staging source offsets (shorts) for this thread's 4 K-chunks and 4 V-chunks
  int bK[4], bV[4];
#pragma unroll
  for (int j = 0; j < 4; ++j){
    int i = tid + j * 256;
    bK[j] = (((i >> 9) * 16 + (i & 15)) * 256) + ((i >> 6) & 7) * 32 + ((i >> 4) & 3) * 8;
    bV[j] = ((i >> 6) * 16 + (i & 15)) * 1024 + ((i >> 4) & 3) * 8;
  }

  // Q fragments for two q-subtiles: lane holds Q[row][c*32 + g*8 + j]
  short8 qfA[8], qfB[8];
#pragma unroll
  for (int c = 0; c < 8; ++c){
    qfA[c] = *(const short8*)(qr + (long)(qb + q15) * D + c * 32 + g * 8);
    qfB[c] = *(const short8*)(qr + (long)(qb + 16 + q15) * D + c * 32 + g * 8);
  }

  f32x4 accA[16], accB[16];
#pragma unroll
  for (int i = 0; i < 16; ++i){
    accA[i] = f32x4{0.f, 0.f, 0.f, 0.f};
    accB[i] = f32x4{0.f, 0.f, 0.f, 0.f};
  }
  float mA = -3e38f, mB = -3e38f, lA = 0.f, lB = 0.f;

  // prologue: stage tile 0 into buf 0
#pragma unroll
  for (int j = 0; j < 4; ++j){
    int i = tid + j * 256;
    gload_lds16(qr + bK[j], &lds[0][i * 8]);
    gload_lds16(vt + bV[j], &lds[0][8192 + i * 8]);
  }
  asm volatile("s_waitcnt vmcnt(0)" ::: "memory");
  __syncthreads();

  int buf = 0;
  for (int kb = 0; kb < T; kb += 32){
    if (kb + 32 < T){
      const unsigned short* sk = qr + (long)(kb + 32) * 256;
      const unsigned short* sv = vt + (kb + 32);
#pragma unroll
      for (int j = 0; j < 4; ++j){
        int i = tid + j * 256;
        gload_lds16(sk + bK[j], &lds[buf ^ 1][i * 8]);
        gload_lds16(sv + bV[j], &lds[buf ^ 1][8192 + i * 8]);
      }
    }
    const short* ldsK = &lds[buf][0];
    const short* ldsV = &lds[buf][8192];

    f32x4 s0a = f32x4{0.f,0.f,0.f,0.f}, s0b = f32x4{0.f,0.f,0.f,0.f};
    f32x4 s1a = f32x4{0.f,0.f,0.f,0.f}, s1b = f32x4{0.f,0.f,0.f,0.f};
#pragma unroll
    for (int c = 0; c < 8; ++c){
      short8 kf0 = *(const short8*)&ldsK[c * 512 + lane * 8];
      short8 kf1 = *(const short8*)&ldsK[4096 + c * 512 + lane * 8];
      s0a = __builtin_amdgcn_mfma_f32_16x16x32_bf16(kf0, qfA[c], s0a, 0, 0, 0);
      s0b = __builtin_amdgcn_mfma_f32_16x16x32_bf16(kf0, qfB[c], s0b, 0, 0, 0);
      s1a = __builtin_amdgcn_mfma_f32_16x16x32_bf16(kf1, qfA[c], s1a, 0, 0, 0);
      s1b = __builtin_amdgcn_mfma_f32_16x16x32_bf16(kf1, qfB[c], s1b, 0, 0, 0);
    }
    short8 paA = softmax_step(s0a, s1a, mA, lA, accA, q15, g);
    short8 paB = softmax_step(s0b, s1b, mB, lB, accB, q15, g);
#pragma unroll
    for (int nc = 0; nc < 16; ++nc){
      short8 vf = *(const short8*)&ldsV[nc * 512 + lane * 8];
      accA[nc] = __builtin_amdgcn_mfma_f32_16x16x32_bf16(paA, vf, accA[nc], 0, 0, 0);
      accB[nc] = __builtin_amdgcn_mfma_f32_16x16x32_bf16(paB, vf, accB[nc], 0, 0, 0);
    }
    asm volatile("s_waitcnt vmcnt(0)" ::: "memory");
    __syncthreads();
    buf ^= 1;
  }

  float* op = Out + (long)head * T * D + (long)qb * D;
  {
    float rl = 1.0f / lA;
    float d0 = __shfl(rl, g * 4 + 0);
    float d1 = __shfl(rl, g * 4 + 1);
    float d2 = __shfl(rl, g * 4 + 2);
    float d3 = __shfl(rl, g * 4 + 3);
#pragma unroll
    for (int nc = 0; nc < 16; ++nc){
      float* o = op + nc * 16 + q15;
      o[(g * 4 + 0) * D] = accA[nc].x * d0;
      o[(g * 4 + 1) * D] = accA[nc].y * d1;
      o[(g * 4 + 2) * D] = accA[nc].z * d2;
      o[(g * 4 + 3) * D] = accA[nc].w * d3;
    }
  }
  {
    float rl = 1.0f / lB;
    float d0 = __shfl(rl, g * 4 + 0);
    float d1 = __shfl(rl, g * 4 + 1);
    float d2 = __shfl(rl, g * 4 + 2);
    float d3 = __shfl(rl, g * 4 + 3);
    float* o2 = op + 16 * D;
#pragma unroll
    for (int nc = 0; nc < 16; ++nc){
      float* o = o2 + nc * 16 + q15;
      o[(g * 4 + 0) * D] = accB[nc].x * d0;
      o[(g * 4 + 1) * D] = accB[nc].y * d1;
      o[(g * 4 + 2) * D] = accB[nc].z * d2;
      o[(g * 4 + 3) * D] = accB[nc].w * d3;
    }
  }
}

extern "C" void kernel_launch(void* const* d_in, const int* in_sizes, int n_in,
                              void* d_out, int out_size, void* d_ws, size_t ws_size,
                              hipStream_t stream){
  (void)in_sizes; (void)n_in; (void)out_size; (void)ws_size;
  const float* Q     = (const float*)d_in[0];
  const float* V     = (const float*)d_in[1];
  const float* freqs = (const float*)d_in[2];
  float* Out = (float*)d_out;
  unsigned short* QR = (unsigned short*)d_ws;                  // [96][1024][256] bf16
  unsigned short* Vt = QR + (size_t)BH * T * D;                // [96][256][1024] bf16
  k_rope<<<dim3((BH * T * D) / 4 / 256), dim3(256), 0, stream>>>(Q, freqs, QR);
  k_transpose<<<dim3(BH * 64), dim3(256), 0, stream>>>(V, Vt);
  k_flash<<<dim3(BH * 8), dim3(256), 0, stream>>>(QR, Vt, Out);
}